// Round 3
// baseline (321.122 us; speedup 1.0000x reference)
//
#include <hip/hip_runtime.h>
#include <hip/hip_bf16.h>

#define NN 2000
#define DD 24
#define JA (DD * DD)          // 576
#define WROW 640              // 576 (2*beta^T) + 24 (alpha) + 24 (2*beta diag) + 16 pad
#define A_OFF JA              // 576
#define DIAG_OFF (JA + DD)    // 600

// ---- pre-pass: W[l][ja] = 2*beta[ja][l]  (tile transpose of a 576 x 2000 matrix)
__global__ __launch_bounds__(256) void k_transpose(const float* __restrict__ beta,
                                                   float* __restrict__ W) {
    __shared__ float t[64][65];
    const int l0 = blockIdx.x * 64, ja0 = blockIdx.y * 64;
    for (int r = threadIdx.y; r < 64; r += 4) {
        int ja = ja0 + r, l = l0 + threadIdx.x;
        if (ja < JA && l < NN) t[r][threadIdx.x] = 2.0f * beta[(size_t)ja * NN + l];
    }
    __syncthreads();
    for (int r = threadIdx.y; r < 64; r += 4) {
        int l = l0 + r, ja = ja0 + threadIdx.x;
        if (l < NN && ja < JA) W[(size_t)l * WROW + ja] = t[threadIdx.x][r];
    }
}

// ---- pre-pass: append alpha and 2*beta[j][j][l] columns to each W row
__global__ __launch_bounds__(256) void k_fill(const float* __restrict__ beta,
                                              const float* __restrict__ alpha,
                                              float* __restrict__ W) {
    int l = blockIdx.x * 256 + threadIdx.x;
    if (l >= NN) return;
    float* w = W + (size_t)l * WROW;
    #pragma unroll
    for (int j = 0; j < DD; ++j) {
        w[A_OFF + j]    = alpha[(size_t)j * NN + l];
        w[DIAG_OFF + j] = 2.0f * beta[(size_t)(j * DD + j) * NN + l];
    }
}

// ---- main: lanes -> i (256 i per block), l-chunk staged in LDS.
// part[lb * (NN*DD) + i*DD + j] = partial over this block's l-range.
template <int MAXL>
__global__ __launch_bounds__(256, 4) void k_pass1_lds(const float* __restrict__ x,
                                                      const float* __restrict__ W,
                                                      float* __restrict__ part,
                                                      int lblk, int lch) {
    __shared__ float wlds[MAXL][WROW];
    __shared__ float xlds[MAXL][DD];

    const int tid = threadIdx.x;
    const int ib  = blockIdx.x;      // 0..7
    const int lb  = blockIdx.y;      // 0..lblk-1
    const int i   = ib * 256 + tid;
    const int ic  = i < NN ? i : NN - 1;

    const int l0 = lb * lch;
    const int nl0 = NN - l0;
    const int nl = nl0 < lch ? (nl0 > 0 ? nl0 : 0) : lch;

    // cooperative stage: W rows (float4) + x rows (float4)
    for (int idx = tid; idx < nl * (WROW / 4); idx += 256) {
        int r = idx / (WROW / 4), c = idx % (WROW / 4);
        reinterpret_cast<float4*>(wlds[r])[c] =
            reinterpret_cast<const float4*>(W + (size_t)(l0 + r) * WROW)[c];
    }
    for (int idx = tid; idx < nl * (DD / 4); idx += 256) {
        int r = idx / (DD / 4), c = idx % (DD / 4);
        reinterpret_cast<float4*>(xlds[r])[c] =
            reinterpret_cast<const float4*>(x + (size_t)(l0 + r) * DD)[c];
    }
    __syncthreads();

    float xi[DD];
    {
        const float4* xr = reinterpret_cast<const float4*>(x + (size_t)ic * DD);
        #pragma unroll
        for (int q = 0; q < DD / 4; ++q) {
            float4 v = xr[q];
            xi[4 * q + 0] = v.x; xi[4 * q + 1] = v.y;
            xi[4 * q + 2] = v.z; xi[4 * q + 3] = v.w;
        }
    }

    float acc[DD];
    #pragma unroll
    for (int j = 0; j < DD; ++j) acc[j] = 0.0f;

    for (int r = 0; r < nl; ++r) {
        const float* __restrict__ w = wlds[r];

        float diff[DD];
        float negS = 0.0f;
        #pragma unroll
        for (int k = 0; k < DD; ++k) {
            float d = xi[k] - xlds[r][k];
            diff[k] = d;
            negS = fmaf(-d, d, negS);
        }

        #pragma unroll
        for (int j = 0; j < DD; ++j) {
            float K = __expf(fmaf(diff[j], diff[j], negS));   // exp(diff_j^2 - S)
            float t = 0.0f;
            const float4* b4 = reinterpret_cast<const float4*>(w + j * DD);
            #pragma unroll
            for (int q = 0; q < DD / 4; ++q) {
                float4 b = b4[q];
                t = fmaf(b.x, diff[4 * q + 0], t);
                t = fmaf(b.y, diff[4 * q + 1], t);
                t = fmaf(b.z, diff[4 * q + 2], t);
                t = fmaf(b.w, diff[4 * q + 3], t);
            }
            t = fmaf(-w[DIAG_OFF + j], diff[j], t);           // drop a==j
            acc[j] = fmaf(K, w[A_OFF + j] + t, acc[j]);
        }
    }

    if (i < NN) {
        float* p = part + (size_t)lb * (NN * DD) + (size_t)i * DD;
        #pragma unroll
        for (int q = 0; q < DD / 4; ++q) {
            float4 v;
            v.x = acc[4 * q + 0]; v.y = acc[4 * q + 1];
            v.z = acc[4 * q + 2]; v.w = acc[4 * q + 3];
            reinterpret_cast<float4*>(p)[q] = v;
        }
    }
}

// ---- mid fallback: global-W pass1 (round-2 structure)
__global__ __launch_bounds__(256) void k_pass1_glb(const float* __restrict__ x,
                                                   const float* __restrict__ W,
                                                   float* __restrict__ part,
                                                   int lblk, int lch) {
    const int tid = threadIdx.x;
    const int i = blockIdx.x * 256 + tid;
    const int ic = i < NN ? i : NN - 1;
    const int lb = blockIdx.y;

    float xi[DD];
    #pragma unroll
    for (int k = 0; k < DD; ++k) xi[k] = x[(size_t)ic * DD + k];
    float acc[DD];
    #pragma unroll
    for (int j = 0; j < DD; ++j) acc[j] = 0.0f;

    const int l0 = lb * lch;
    const int l1 = (l0 + lch) < NN ? (l0 + lch) : NN;
    for (int l = l0; l < l1; ++l) {
        const float* __restrict__ w = W + (size_t)l * WROW;
        float diff[DD]; float negS = 0.0f;
        #pragma unroll
        for (int k = 0; k < DD; ++k) {
            float d = xi[k] - x[(size_t)l * DD + k];
            diff[k] = d; negS = fmaf(-d, d, negS);
        }
        #pragma unroll
        for (int j = 0; j < DD; ++j) {
            float K = __expf(fmaf(diff[j], diff[j], negS));
            float t = 0.0f;
            const float* bj = w + j * DD;
            #pragma unroll
            for (int a = 0; a < DD; ++a) t = fmaf(bj[a], diff[a], t);
            t = fmaf(-w[DIAG_OFF + j], diff[j], t);
            acc[j] = fmaf(K, w[A_OFF + j] + t, acc[j]);
        }
    }
    if (i < NN) {
        float* p = part + (size_t)lb * (NN * DD) + (size_t)i * DD;
        #pragma unroll
        for (int j = 0; j < DD; ++j) p[j] = acc[j];
    }
}

// ---- reduce partials over lblk slabs
__global__ __launch_bounds__(256) void k_pass2(const float* __restrict__ part,
                                               float* __restrict__ out, int lblk) {
    int m = blockIdx.x * 256 + threadIdx.x;
    if (m >= NN * DD) return;
    float s = 0.0f;
    for (int b = 0; b < lblk; ++b)
        s += part[(size_t)b * (NN * DD) + m];
    out[m] = s;
}

extern "C" void kernel_launch(void* const* d_in, const int* in_sizes, int n_in,
                              void* d_out, int out_size, void* d_ws, size_t ws_size,
                              hipStream_t stream) {
    const float* x     = (const float*)d_in[0];   // [2000, 24]
    const float* alpha = (const float*)d_in[1];   // [24, 2000]
    const float* beta  = (const float*)d_in[2];   // [24, 24, 2000]
    float* out = (float*)d_out;                   // [2000, 24]

    const size_t WBYTES = (size_t)NN * WROW * sizeof(float);   // 5.12 MB
    const size_t SLAB   = (size_t)NN * DD * sizeof(float);     // 192 KB

    float* W    = (float*)d_ws;
    float* part = (float*)((char*)d_ws + WBYTES);

    if (ws_size >= WBYTES + 250 * SLAB) {
        // lch=8, lblk=250: 2000 blocks, 31 waves/CU target, LDS 21 KB/block
        dim3 tb(64, 4);
        k_transpose<<<dim3(32, 9), tb, 0, stream>>>(beta, W);
        k_fill<<<(NN + 255) / 256, 256, 0, stream>>>(beta, alpha, W);
        k_pass1_lds<8><<<dim3(8, 250), 256, 0, stream>>>(x, W, part, 250, 8);
        k_pass2<<<(NN * DD + 255) / 256, 256, 0, stream>>>(part, out, 250);
    } else if (ws_size >= WBYTES + 125 * SLAB) {
        // lch=16, lblk=125: 1000 blocks, LDS 42 KB/block
        dim3 tb(64, 4);
        k_transpose<<<dim3(32, 9), tb, 0, stream>>>(beta, W);
        k_fill<<<(NN + 255) / 256, 256, 0, stream>>>(beta, alpha, W);
        k_pass1_lds<16><<<dim3(8, 125), 256, 0, stream>>>(x, W, part, 125, 16);
        k_pass2<<<(NN * DD + 255) / 256, 256, 0, stream>>>(part, out, 125);
    } else if (ws_size >= WBYTES + 64 * SLAB) {
        // round-2 structure
        dim3 tb(64, 4);
        k_transpose<<<dim3(32, 9), tb, 0, stream>>>(beta, W);
        k_fill<<<(NN + 255) / 256, 256, 0, stream>>>(beta, alpha, W);
        k_pass1_glb<<<dim3(8, 64), 256, 0, stream>>>(x, W, part, 64, 32);
        k_pass2<<<(NN * DD + 255) / 256, 256, 0, stream>>>(part, out, 64);
    } else {
        // minimal: single l-chunk per i-block, direct accumulate to out
        int lblk = 16;
        while (lblk > 1 && (size_t)lblk * SLAB > ws_size) lblk >>= 1;
        int lch = (NN + lblk - 1) / lblk;
        float* p0 = (float*)d_ws;
        k_pass1_glb<<<dim3(8, lblk), 256, 0, stream>>>(x, (float*)d_in[2], p0, lblk, lch); // degenerate, unlikely
        k_pass2<<<(NN * DD + 255) / 256, 256, 0, stream>>>(p0, out, lblk);
    }
}

// Round 4
// 194.037 us; speedup vs baseline: 1.6550x; 1.6550x over previous
//
#include <hip/hip_runtime.h>
#include <hip/hip_bf16.h>

#define NN 2000
#define DD 24
#define JA (DD * DD)          // 576
#define WROW 640              // 576 (2*beta^T) + 24 (alpha) + 24 (2*beta diag) + 16 pad
#define A_OFF JA              // 576
#define DIAG_OFF (JA + DD)    // 600
#define JW 6                  // j's per wave (4 waves * 6 = 24)

// ---- pre-pass: W[l][ja] = 2*beta[ja][l]  (tile transpose of a 576 x 2000 matrix)
__global__ __launch_bounds__(256) void k_transpose(const float* __restrict__ beta,
                                                   float* __restrict__ W) {
    __shared__ float t[64][65];
    const int l0 = blockIdx.x * 64, ja0 = blockIdx.y * 64;
    for (int r = threadIdx.y; r < 64; r += 4) {
        int ja = ja0 + r, l = l0 + threadIdx.x;
        if (ja < JA && l < NN) t[r][threadIdx.x] = 2.0f * beta[(size_t)ja * NN + l];
    }
    __syncthreads();
    for (int r = threadIdx.y; r < 64; r += 4) {
        int l = l0 + r, ja = ja0 + threadIdx.x;
        if (l < NN && ja < JA) W[(size_t)l * WROW + ja] = t[threadIdx.x][r];
    }
}

// ---- pre-pass: append alpha and 2*beta[j][j][l] columns to each W row
__global__ __launch_bounds__(256) void k_fill(const float* __restrict__ beta,
                                              const float* __restrict__ alpha,
                                              float* __restrict__ W) {
    int l = blockIdx.x * 256 + threadIdx.x;
    if (l >= NN) return;
    float* w = W + (size_t)l * WROW;
    #pragma unroll
    for (int j = 0; j < DD; ++j) {
        w[A_OFF + j]    = alpha[(size_t)j * NN + l];
        w[DIAG_OFF + j] = 2.0f * beta[(size_t)(j * DD + j) * NN + l];
    }
}

// ---- inner l-loop for one wave's 6 compile-time j's. Low register pressure:
// xi[24] + diff[24] + acc[6] + temps ~ 70 VGPRs, no spills.
template <int J0>
__device__ __forceinline__ void run_j6(const float* __restrict__ x,
                                       const float* __restrict__ W,
                                       float* __restrict__ part,
                                       const float (&xi)[DD],
                                       int i, int lb, int l0, int l1) {
    float acc[JW];
    #pragma unroll
    for (int q = 0; q < JW; ++q) acc[q] = 0.0f;

    #pragma unroll 1
    for (int l = l0; l < l1; ++l) {
        const float* __restrict__ w  = W + (size_t)l * WROW;   // block-uniform
        const float* __restrict__ xl = x + (size_t)l * DD;     // block-uniform

        float diff[DD];
        float negS = 0.0f;
        #pragma unroll
        for (int k = 0; k < DD; ++k) {
            float d = xi[k] - xl[k];
            diff[k] = d;
            negS = fmaf(-d, d, negS);
        }

        #pragma unroll
        for (int q = 0; q < JW; ++q) {
            const int j = J0 + q;                       // compile-time
            float dj = diff[j];
            float K  = __expf(fmaf(dj, dj, negS));      // exp(diff_j^2 - S)
            const float* bj = w + j * DD;               // 2*beta[j][a], contiguous
            float t0 = 0.f, t1 = 0.f, t2 = 0.f, t3 = 0.f;
            #pragma unroll
            for (int a = 0; a < DD; a += 4) {
                t0 = fmaf(bj[a + 0], diff[a + 0], t0);
                t1 = fmaf(bj[a + 1], diff[a + 1], t1);
                t2 = fmaf(bj[a + 2], diff[a + 2], t2);
                t3 = fmaf(bj[a + 3], diff[a + 3], t3);
            }
            float t = (t0 + t1) + (t2 + t3);
            t = fmaf(-w[DIAG_OFF + j], dj, t);          // drop a==j
            acc[q] = fmaf(K, w[A_OFF + j] + t, acc[q]);
        }
    }

    if (i < NN) {
        #pragma unroll
        for (int q = 0; q < JW; ++q)
            part[((size_t)lb * DD + (J0 + q)) * NN + i] = acc[q];  // [lb][j][i], coalesced in i
    }
}

// ---- main: block = 4 waves; lanes -> 64 consecutive i; wave w -> j in [6w, 6w+6).
// part[lb][j][i] = partial over this lb's l-range.
__global__ __launch_bounds__(256, 4) void k_pass1_js(const float* __restrict__ x,
                                                     const float* __restrict__ W,
                                                     float* __restrict__ part,
                                                     int lch) {
    const int tid  = threadIdx.x;
    const int wave = tid >> 6;
    const int lane = tid & 63;
    const int i    = blockIdx.x * 64 + lane;     // blockIdx.x in [0,32)
    const int ic   = i < NN ? i : NN - 1;
    const int lb   = blockIdx.y;

    float xi[DD];
    {
        const float4* xr = reinterpret_cast<const float4*>(x + (size_t)ic * DD);
        #pragma unroll
        for (int q = 0; q < DD / 4; ++q) {
            float4 v = xr[q];
            xi[4 * q + 0] = v.x; xi[4 * q + 1] = v.y;
            xi[4 * q + 2] = v.z; xi[4 * q + 3] = v.w;
        }
    }

    const int l0 = lb * lch;
    int l1 = l0 + lch; if (l1 > NN) l1 = NN;

    // wave-uniform branch, hoisted outside the l-loop
    if      (wave == 0) run_j6<0 >(x, W, part, xi, i, lb, l0, l1);
    else if (wave == 1) run_j6<6 >(x, W, part, xi, i, lb, l0, l1);
    else if (wave == 2) run_j6<12>(x, W, part, xi, i, lb, l0, l1);
    else                run_j6<18>(x, W, part, xi, i, lb, l0, l1);
}

// ---- reduce partials over lblk slabs; slab layout [j][i] (offset m = j*NN+i)
__global__ __launch_bounds__(256) void k_pass2t(const float* __restrict__ part,
                                                float* __restrict__ out, int lblk) {
    int m = blockIdx.x * 256 + threadIdx.x;
    if (m >= NN * DD) return;
    float s = 0.0f;
    for (int b = 0; b < lblk; ++b)
        s += part[(size_t)b * (NN * DD) + m];
    int j = m / NN, i = m - j * NN;
    out[(size_t)i * DD + j] = s;
}

extern "C" void kernel_launch(void* const* d_in, const int* in_sizes, int n_in,
                              void* d_out, int out_size, void* d_ws, size_t ws_size,
                              hipStream_t stream) {
    const float* x     = (const float*)d_in[0];   // [2000, 24]
    const float* alpha = (const float*)d_in[1];   // [24, 2000]
    const float* beta  = (const float*)d_in[2];   // [24, 24, 2000]
    float* out = (float*)d_out;                   // [2000, 24]

    const size_t WBYTES = (size_t)NN * WROW * sizeof(float);   // 5.12 MB
    const size_t SLAB   = (size_t)NN * DD * sizeof(float);     // 192 KB

    float* W    = (float*)d_ws;
    float* part = (float*)((char*)d_ws + WBYTES);

    // pick largest lblk (power-of-2-ish) that fits; ws proven >= 53 MB so 64 expected
    int lblk = 64;
    while (lblk > 1 && WBYTES + (size_t)lblk * SLAB > ws_size) lblk >>= 1;
    int lch = (NN + lblk - 1) / lblk;

    dim3 tb(64, 4);
    k_transpose<<<dim3(32, 9), tb, 0, stream>>>(beta, W);
    k_fill<<<(NN + 255) / 256, 256, 0, stream>>>(beta, alpha, W);
    k_pass1_js<<<dim3(32, lblk), 256, 0, stream>>>(x, W, part, lch);
    k_pass2t<<<(NN * DD + 255) / 256, 256, 0, stream>>>(part, out, lblk);
}

// Round 5
// 98.384 us; speedup vs baseline: 3.2640x; 1.9722x over previous
//
#include <hip/hip_runtime.h>
#include <hip/hip_bf16.h>

#define NN 2000
#define DD 24
#define JA 576
#define WROW 640              // 576 (2*beta^T) + 24 (alpha) + 24 (2*beta diag) + 16 pad
#define A_OFF 576
#define DIAG_OFF 600
#define NSLAB 125             // l-slabs, LCH each
#define LCH 16                // 125 * 16 = 2000
#define IDXCAP 2048
#define THRESH 16.0f          // keep pair if S - max_j diff_j^2 <= THRESH (K >= e^-16)

// ---- prep: W[l][ja]=2*beta[ja][l] transpose (y<9) + alpha/diag fill (y==9)
__global__ __launch_bounds__(256) void k_prep(const float* __restrict__ beta,
                                              const float* __restrict__ alpha,
                                              float* __restrict__ W) {
    if (blockIdx.y < 9) {
        __shared__ float t[64][65];
        const int l0 = blockIdx.x * 64, ja0 = blockIdx.y * 64;
        for (int r = threadIdx.y; r < 64; r += 4) {
            int ja = ja0 + r, l = l0 + threadIdx.x;
            if (ja < JA && l < NN) t[r][threadIdx.x] = 2.0f * beta[(size_t)ja * NN + l];
        }
        __syncthreads();
        for (int r = threadIdx.y; r < 64; r += 4) {
            int l = l0 + r, ja = ja0 + threadIdx.x;
            if (l < NN && ja < JA) W[(size_t)l * WROW + ja] = t[threadIdx.x][r];
        }
    } else {
        int tid = threadIdx.y * 64 + threadIdx.x;
        int l = blockIdx.x * 64 + (tid & 63);
        int rep = tid >> 6;                       // 0..3 -> j = 6*rep .. 6*rep+5
        if (l < NN) {
            float* w = W + (size_t)l * WROW;
            #pragma unroll
            for (int q = 0; q < 6; ++q) {
                int j = rep * 6 + q;
                w[A_OFF + j]    = alpha[(size_t)j * NN + l];
                w[DIAG_OFF + j] = 2.0f * beta[(size_t)(j * DD + j) * NN + l];
            }
        }
    }
}

// ---- pass A: per-l compacted list of passing i's. One wave per l. Deterministic
// (ballot + prefix-popcount, i ascending).
__global__ __launch_bounds__(256) void k_passA(const float* __restrict__ x,
                                               int* __restrict__ cnt,
                                               unsigned short* __restrict__ idx) {
    const int wave = threadIdx.x >> 6, lane = threadIdx.x & 63;
    const int l = blockIdx.x * 4 + wave;          // 500 blocks * 4 = 2000
    float xl[DD];
    {
        const float* xr = x + (size_t)l * DD;
        #pragma unroll
        for (int k = 0; k < DD; ++k) xl[k] = xr[k];
    }
    unsigned short* row = idx + (size_t)l * IDXCAP;
    int base = 0;
    for (int c = 0; c < 32; ++c) {
        int i = c * 64 + lane;
        bool valid = i < NN;
        int ic = valid ? i : 0;
        const float4* xv = reinterpret_cast<const float4*>(x + (size_t)ic * DD);
        float S = 0.f, m2 = 0.f;
        #pragma unroll
        for (int q = 0; q < 6; ++q) {
            float4 v = xv[q];
            float d0 = v.x - xl[4*q+0], d1 = v.y - xl[4*q+1];
            float d2 = v.z - xl[4*q+2], d3 = v.w - xl[4*q+3];
            d0 *= d0; d1 *= d1; d2 *= d2; d3 *= d3;
            S += (d0 + d1) + (d2 + d3);
            m2 = fmaxf(m2, fmaxf(fmaxf(d0, d1), fmaxf(d2, d3)));
        }
        bool pred = valid && (S - m2 <= THRESH);
        unsigned long long mask = __ballot(pred);
        if (pred) {
            int rank = __popcll(mask & ((1ull << lane) - 1ull));
            row[base + rank] = (unsigned short)i;
        }
        base += __popcll(mask);
    }
    if (lane == 0) cnt[l] = base;
}

// ---- pass B body: one (slab, jgroup) block. Zero-inits its private region,
// then for each l in slab: lanes -> list entries, RMW accumulate 6 j-columns.
// Race-free: within l entries are distinct i; barrier between l's; jgroups
// write disjoint regions. Deterministic (l ascending, fixed lane->entry map).
template <int J0>
__device__ __forceinline__ void passB_body(const float* __restrict__ x,
                                           const float* __restrict__ W,
                                           const int* __restrict__ cnt,
                                           const unsigned short* __restrict__ idx,
                                           float* __restrict__ reg,  // [NN][6]
                                           int l0, int l1) {
    const int tid = threadIdx.x, wave = tid >> 6, lane = tid & 63;

    // zero own region: NN*6 = 12000 floats
    for (int m = tid; m < NN * 6; m += 256) reg[m] = 0.0f;
    __syncthreads();

    #pragma unroll 1
    for (int l = l0; l < l1; ++l) {
        const int c = cnt[l];
        const float* __restrict__ w = W + (size_t)l * WROW;
        float xl[DD];
        {
            const float* xr = x + (size_t)l * DD;
            #pragma unroll
            for (int k = 0; k < DD; ++k) xl[k] = xr[k];
        }
        const unsigned short* row = idx + (size_t)l * IDXCAP;

        for (int base = wave * 64; base < c; base += 256) {
            int e = base + lane;
            bool v = e < c;
            int i = v ? (int)row[e] : 0;
            const float4* xv = reinterpret_cast<const float4*>(x + (size_t)i * DD);
            float diff[DD];
            float negS = 0.f;
            #pragma unroll
            for (int q = 0; q < 6; ++q) {
                float4 vv = xv[q];
                float d0 = vv.x - xl[4*q+0], d1 = vv.y - xl[4*q+1];
                float d2 = vv.z - xl[4*q+2], d3 = vv.w - xl[4*q+3];
                diff[4*q+0] = d0; diff[4*q+1] = d1;
                diff[4*q+2] = d2; diff[4*q+3] = d3;
                negS = fmaf(-d0, d0, negS); negS = fmaf(-d1, d1, negS);
                negS = fmaf(-d2, d2, negS); negS = fmaf(-d3, d3, negS);
            }
            float val[6];
            #pragma unroll
            for (int q = 0; q < 6; ++q) {
                const int j = J0 + q;                    // compile-time
                float dj = diff[j];
                float K = __expf(fmaf(dj, dj, negS));    // exp(diff_j^2 - S)
                const float* bj = w + j * DD;
                float t0 = 0.f, t1 = 0.f, t2 = 0.f, t3 = 0.f;
                #pragma unroll
                for (int a = 0; a < DD; a += 4) {
                    t0 = fmaf(bj[a + 0], diff[a + 0], t0);
                    t1 = fmaf(bj[a + 1], diff[a + 1], t1);
                    t2 = fmaf(bj[a + 2], diff[a + 2], t2);
                    t3 = fmaf(bj[a + 3], diff[a + 3], t3);
                }
                float t = (t0 + t1) + (t2 + t3);
                t = fmaf(-w[DIAG_OFF + j], dj, t);       // drop a==j
                val[q] = K * (w[A_OFF + j] + t);
            }
            if (v) {
                float2* pp = reinterpret_cast<float2*>(reg + (size_t)i * 6);
                float2 a0 = pp[0], a1 = pp[1], a2 = pp[2];
                a0.x += val[0]; a0.y += val[1];
                a1.x += val[2]; a1.y += val[3];
                a2.x += val[4]; a2.y += val[5];
                pp[0] = a0; pp[1] = a1; pp[2] = a2;
            }
        }
        __syncthreads();
    }
}

__global__ __launch_bounds__(256, 2) void k_passB(const float* __restrict__ x,
                                                  const float* __restrict__ W,
                                                  const int* __restrict__ cnt,
                                                  const unsigned short* __restrict__ idx,
                                                  float* __restrict__ part) {
    const int s = blockIdx.x;                     // 0..NSLAB-1
    const int g = blockIdx.y;                     // 0..3
    const int l0 = s * LCH;
    const int l1 = min(l0 + LCH, NN);
    float* reg = part + ((size_t)(s * 4 + g) * NN) * 6;   // private [NN][6]
    if      (g == 0) passB_body<0 >(x, W, cnt, idx, reg, l0, l1);
    else if (g == 1) passB_body<6 >(x, W, cnt, idx, reg, l0, l1);
    else if (g == 2) passB_body<12>(x, W, cnt, idx, reg, l0, l1);
    else             passB_body<18>(x, W, cnt, idx, reg, l0, l1);
}

// ---- pass C: out[i][j] = sum_s part[(s*4 + j/6)][i][j%6]
__global__ __launch_bounds__(256) void k_passC(const float* __restrict__ part,
                                               float* __restrict__ out) {
    int m = blockIdx.x * 256 + threadIdx.x;
    if (m >= NN * DD) return;
    int i = m / DD, j = m - i * DD;
    int g = j / 6, q = j - g * 6;
    const float* p = part + ((size_t)g * NN + i) * 6 + q;
    float acc = 0.f;
    #pragma unroll 5
    for (int s = 0; s < NSLAB; ++s)
        acc += p[(size_t)s * 4 * NN * 6];
    out[m] = acc;
}

// ================= round-4 fallback (proven) =================
template <int J0>
__device__ __forceinline__ void run_j6(const float* __restrict__ x,
                                       const float* __restrict__ W,
                                       float* __restrict__ part,
                                       const float (&xi)[DD],
                                       int i, int lb, int l0, int l1) {
    float acc[6];
    #pragma unroll
    for (int q = 0; q < 6; ++q) acc[q] = 0.0f;
    #pragma unroll 1
    for (int l = l0; l < l1; ++l) {
        const float* __restrict__ w  = W + (size_t)l * WROW;
        const float* __restrict__ xl = x + (size_t)l * DD;
        float diff[DD]; float negS = 0.0f;
        #pragma unroll
        for (int k = 0; k < DD; ++k) {
            float d = xi[k] - xl[k];
            diff[k] = d; negS = fmaf(-d, d, negS);
        }
        #pragma unroll
        for (int q = 0; q < 6; ++q) {
            const int j = J0 + q;
            float dj = diff[j];
            float K = __expf(fmaf(dj, dj, negS));
            const float* bj = w + j * DD;
            float t0=0.f,t1=0.f,t2=0.f,t3=0.f;
            #pragma unroll
            for (int a = 0; a < DD; a += 4) {
                t0 = fmaf(bj[a+0], diff[a+0], t0);
                t1 = fmaf(bj[a+1], diff[a+1], t1);
                t2 = fmaf(bj[a+2], diff[a+2], t2);
                t3 = fmaf(bj[a+3], diff[a+3], t3);
            }
            float t = (t0+t1)+(t2+t3);
            t = fmaf(-w[DIAG_OFF+j], dj, t);
            acc[q] = fmaf(K, w[A_OFF+j] + t, acc[q]);
        }
    }
    if (i < NN) {
        #pragma unroll
        for (int q = 0; q < 6; ++q)
            part[((size_t)lb * DD + (J0+q)) * NN + i] = acc[q];
    }
}

__global__ __launch_bounds__(256, 4) void k_pass1_js(const float* __restrict__ x,
                                                     const float* __restrict__ W,
                                                     float* __restrict__ part,
                                                     int lch) {
    const int tid  = threadIdx.x;
    const int wave = tid >> 6, lane = tid & 63;
    const int i  = blockIdx.x * 64 + lane;
    const int ic = i < NN ? i : NN - 1;
    const int lb = blockIdx.y;
    float xi[DD];
    {
        const float4* xr = reinterpret_cast<const float4*>(x + (size_t)ic * DD);
        #pragma unroll
        for (int q = 0; q < DD/4; ++q) {
            float4 v = xr[q];
            xi[4*q+0]=v.x; xi[4*q+1]=v.y; xi[4*q+2]=v.z; xi[4*q+3]=v.w;
        }
    }
    const int l0 = lb * lch;
    int l1 = l0 + lch; if (l1 > NN) l1 = NN;
    if      (wave == 0) run_j6<0 >(x, W, part, xi, i, lb, l0, l1);
    else if (wave == 1) run_j6<6 >(x, W, part, xi, i, lb, l0, l1);
    else if (wave == 2) run_j6<12>(x, W, part, xi, i, lb, l0, l1);
    else                run_j6<18>(x, W, part, xi, i, lb, l0, l1);
}

__global__ __launch_bounds__(256) void k_pass2t(const float* __restrict__ part,
                                                float* __restrict__ out, int lblk) {
    int m = blockIdx.x * 256 + threadIdx.x;
    if (m >= NN * DD) return;
    float s = 0.0f;
    for (int b = 0; b < lblk; ++b)
        s += part[(size_t)b * (NN * DD) + m];
    int j = m / NN, i = m - j * NN;
    out[(size_t)i * DD + j] = s;
}
// ================= end fallback =================

extern "C" void kernel_launch(void* const* d_in, const int* in_sizes, int n_in,
                              void* d_out, int out_size, void* d_ws, size_t ws_size,
                              hipStream_t stream) {
    const float* x     = (const float*)d_in[0];   // [2000, 24]
    const float* alpha = (const float*)d_in[1];   // [24, 2000]
    const float* beta  = (const float*)d_in[2];   // [24, 24, 2000]
    float* out = (float*)d_out;                   // [2000, 24]

    const size_t WBYTES   = (size_t)NN * WROW * 4;                 // 5,120,000
    const size_t CNT_OFF  = WBYTES;                                // ints [2000]
    const size_t IDX_OFF  = CNT_OFF + 8192;                        // ushort [2000][2048]
    const size_t IDXBYTES = (size_t)NN * IDXCAP * 2;               // 8,192,000
    const size_t PART_OFF = IDX_OFF + IDXBYTES;                    // 13,320,192
    const size_t PARTBYTES = (size_t)NSLAB * 4 * NN * 6 * 4;       // 24,000,000
    const size_t NEED = PART_OFF + PARTBYTES;                      // ~37.3 MB

    float* W = (float*)d_ws;

    if (ws_size >= NEED) {
        int* cnt = (int*)((char*)d_ws + CNT_OFF);
        unsigned short* idx = (unsigned short*)((char*)d_ws + IDX_OFF);
        float* part = (float*)((char*)d_ws + PART_OFF);

        k_prep<<<dim3(32, 10), dim3(64, 4), 0, stream>>>(beta, alpha, W);
        k_passA<<<500, 256, 0, stream>>>(x, cnt, idx);
        k_passB<<<dim3(NSLAB, 4), 256, 0, stream>>>(x, W, cnt, idx, part);
        k_passC<<<(NN * DD + 255) / 256, 256, 0, stream>>>(part, out);
    } else {
        // proven round-4 path
        const size_t SLAB = (size_t)NN * DD * 4;
        float* part = (float*)((char*)d_ws + WBYTES);
        int lblk = 64;
        while (lblk > 1 && WBYTES + (size_t)lblk * SLAB > ws_size) lblk >>= 1;
        int lch = (NN + lblk - 1) / lblk;
        k_prep<<<dim3(32, 10), dim3(64, 4), 0, stream>>>(beta, alpha, W);
        k_pass1_js<<<dim3(32, lblk), 256, 0, stream>>>(x, W, part, lch);
        k_pass2t<<<(NN * DD + 255) / 256, 256, 0, stream>>>(part, out, lblk);
    }
}